// Round 21
// baseline (16866.913 us; speedup 1.0000x reference)
//
#include <hip/hip_runtime.h>

typedef unsigned short ushort_t;
typedef short sh8 __attribute__((ext_vector_type(8)));     // 8 bf16 (4 VGPR)
typedef float f32x4 __attribute__((ext_vector_type(4)));   // 4 fp32 acc

#define MFMA16(a,b,c) __builtin_amdgcn_mfma_f32_16x16x32_bf16((a),(b),(c),0,0,0)

#define SEQL   512
#define BATCH  64
#define HDIM   1024
#define G3     3072
#define AROWS  (SEQL*BATCH)          // 32768
#define YSZ    (SEQL*BATCH*HDIM)     // 33554432
#define BH     (BATCH*HDIM)          // 65536
#define NWGR   256                   // rec WGs: 4 groups x 64

__device__ __forceinline__ ushort_t f2bf(float x) {
  unsigned u = __float_as_uint(x);
  u += 0x7FFFu + ((u >> 16) & 1u);    // RNE
  return (ushort_t)(u >> 16);
}
__device__ __forceinline__ float bf2f(ushort_t h) {
  return __uint_as_float(((unsigned)h) << 16);
}

// ---------------- conversion / init (Wih + h0 only; Whh converted in rec LDS fill) ----------------
__global__ void cvt_kernel(const float* __restrict__ wih, const float* __restrict__ h0,
                           ushort_t* __restrict__ WihH, ushort_t* __restrict__ WihL,
                           ushort_t* __restrict__ hH) {
  const int NW = G3 * HDIM;
  int i0 = blockIdx.x * blockDim.x + threadIdx.x;
  int stride = gridDim.x * blockDim.x;
  for (int i = i0; i < NW; i += stride) {
    float x = wih[i]; ushort_t h = f2bf(x);
    WihH[i] = h; WihL[i] = f2bf(x - bf2f(h));
  }
  for (int i = i0; i < BH; i += stride) {
    hH[i] = f2bf(h0[i]);
  }
}

// ---------------- phase 1: gx = input @ W_ih^T + b_ih (2-term, R19-measured) ----------------
__global__ __launch_bounds__(256) void gemm_gx(
    const float* __restrict__ A,            // [32768][1024] fp32
    const ushort_t* __restrict__ BHp, const ushort_t* __restrict__ BLp, // [3072][1024]
    const float* __restrict__ bias,         // [3072]
    float* __restrict__ gx)                 // [32768][3072]
{
  int bid = blockIdx.x;
  int mt = bid / 24, nt = bid % 24;
  int w = threadIdx.x >> 6, l = threadIdx.x & 63;
  int lr = l & 15, lk = (l >> 4) * 8;

  f32x4 acc[2][8];
  #pragma unroll
  for (int mi = 0; mi < 2; ++mi)
    #pragma unroll
    for (int ni = 0; ni < 8; ++ni) acc[mi][ni] = (f32x4){0.f, 0.f, 0.f, 0.f};

  int arow0 = mt * 128 + w * 32 + lr;
  int brow0 = nt * 128 + lr;

  for (int k0 = 0; k0 < HDIM; k0 += 32) {
    int ka = k0 + lk;
    sh8 aH[2];
    #pragma unroll
    for (int mi = 0; mi < 2; ++mi) {
      const float* ap = A + (size_t)(arow0 + mi * 16) * HDIM + ka;
      float4 x0 = *(const float4*)ap;
      float4 x1 = *(const float4*)(ap + 4);
      float xs[8] = {x0.x, x0.y, x0.z, x0.w, x1.x, x1.y, x1.z, x1.w};
      #pragma unroll
      for (int j = 0; j < 8; ++j) aH[mi][j] = (short)f2bf(xs[j]);
    }
    #pragma unroll
    for (int ni = 0; ni < 8; ++ni) {
      const ushort_t* bh = BHp + (size_t)(brow0 + ni * 16) * HDIM + ka;
      const ushort_t* bl = BLp + (size_t)(brow0 + ni * 16) * HDIM + ka;
      sh8 bHf = *(const sh8*)bh;
      sh8 bLf = *(const sh8*)bl;
      #pragma unroll
      for (int mi = 0; mi < 2; ++mi) {
        acc[mi][ni] = MFMA16(aH[mi], bHf, acc[mi][ni]);
        acc[mi][ni] = MFMA16(aH[mi], bLf, acc[mi][ni]);
      }
    }
  }
  int rb = (l >> 4) * 4;
  #pragma unroll
  for (int mi = 0; mi < 2; ++mi)
    #pragma unroll
    for (int ni = 0; ni < 8; ++ni) {
      int col = nt * 128 + ni * 16 + lr;
      float b = bias[col];
      #pragma unroll
      for (int j = 0; j < 4; ++j) {
        int row = mt * 128 + w * 32 + mi * 16 + rb + j;
        __builtin_nontemporal_store(acc[mi][ni][j] + b, &gx[(size_t)row * G3 + col]);
      }
    }
}

// ---------------- group-local flat slot barrier (R11 protocol, per-group offset) ----------------
__device__ __forceinline__ void gbar_grp(unsigned* slots, int q, int jj, int tid, unsigned e) {
  __syncthreads();
  if (tid < 64) {
    unsigned* base = slots + (size_t)q * 64 * 32;
    if (tid == 0)
      __hip_atomic_store(base + jj * 32, e, __ATOMIC_RELEASE, __HIP_MEMORY_SCOPE_AGENT);
    unsigned* sp = base + tid * 32;
    while (__hip_atomic_load(sp, __ATOMIC_RELAXED, __HIP_MEMORY_SCOPE_AGENT) < e)
      __builtin_amdgcn_s_sleep(1);
    (void)__hip_atomic_load(sp, __ATOMIC_ACQUIRE, __HIP_MEMORY_SCOPE_AGENT);
  }
  __syncthreads();
}

// ---------------- phase 2: recurrence, 4 independent groups x 64 WGs ----------------
// Group q (WGs 64q..64q+63) owns batch rows [16q,16q+16). WG jj owns hidden cols [16jj,16jj+16).
// Weights in LDS (128KB, identical layout/replication across groups): rH@0,zH@32K,nH@64K,nL@96K.
// Waves split K into quarters (8 k-iters each); partials reduced via LDS scratch @128K.
// Wave 0 does all elementwise work + stores; exchange (hH,rhH) normal stores (R11 config).
__global__ __launch_bounds__(256, 1) void gru_rec(
    const float* __restrict__ gx,                 // [512][64][3072]
    const float* __restrict__ whh,                // [3072][1024] fp32
    const float* __restrict__ bhh,
    const float* __restrict__ h0f,                // [64][1024] fp32
    ushort_t* __restrict__ hH,                    // [2][64][1024]
    ushort_t* __restrict__ rhH,                   // [64][1024]
    float* __restrict__ Y, float* __restrict__ Yh,
    unsigned* __restrict__ slots)                 // 256 x 128B
{
  extern __shared__ char lds[];
  const int g = blockIdx.x;
  const int q = g >> 6;          // group (batch rows 16q..16q+16)
  const int jj = g & 63;         // col owner
  const int tid = threadIdx.x;
  const int w = tid >> 6, l = tid & 63;
  const int lr = l & 15, lk = (l >> 4) * 8, rb = (l >> 4) * 4;
  const int c0 = jj * 16;
  const int c = c0 + lr;
  const int b0 = q * 16;

  // ---- LDS weight fill from fp32 whh (on-the-fly f2bf), swizzle byte ^= (row&7)<<4 ----
  #pragma unroll
  for (int p = 0; p < 32; ++p) {
    int qq = tid + p * 256;
    int flat = qq * 16;
    int lrow = flat >> 11;
    int off = flat & 2047;
    int dst = flat ^ ((lrow & 7) << 4);
    int col = off >> 1;
    const float* src;
    bool lo = false;
    if (lrow < 16)      src = whh + (size_t)(c0 + lrow) * HDIM + col;
    else if (lrow < 32) src = whh + (size_t)(1024 + c0 + lrow - 16) * HDIM + col;
    else if (lrow < 48) src = whh + (size_t)(2048 + c0 + lrow - 32) * HDIM + col;
    else              { src = whh + (size_t)(2048 + c0 + lrow - 48) * HDIM + col; lo = true; }
    float4 x0 = *(const float4*)src;
    float4 x1 = *(const float4*)(src + 4);
    float xs[8] = {x0.x, x0.y, x0.z, x0.w, x1.x, x1.y, x1.z, x1.w};
    union { ushort_t v[8]; sh8 s; } pk;
    #pragma unroll
    for (int j = 0; j < 8; ++j) {
      ushort_t hi = f2bf(xs[j]);
      pk.v[j] = lo ? f2bf(xs[j] - bf2f(hi)) : hi;
    }
    *(sh8*)(lds + dst) = pk.s;
  }
  f32x4* sR = (f32x4*)(lds + 131072);            // [4][64] partials
  f32x4* sZ = (f32x4*)(lds + 131072 + 4096);     // [4][64]
  __syncthreads();

  const float br = bhh[c], bz = bhh[1024 + c], bn = bhh[2048 + c];
  unsigned bar = 0;

  // wave-0-only state
  float hold[4], zreg[4], gxr[4], gxz[4], gxn[4];
  if (w == 0) {
    #pragma unroll
    for (int j = 0; j < 4; ++j) {
      int b = b0 + rb + j;
      hold[j] = h0f[b * HDIM + c];
      gxr[j] = __builtin_nontemporal_load(gx + (size_t)b * G3 + c);
      gxz[j] = __builtin_nontemporal_load(gx + (size_t)b * G3 + 1024 + c);
      gxn[j] = __builtin_nontemporal_load(gx + (size_t)b * G3 + 2048 + c);
    }
  }

  for (int t = 0; t < SEQL; ++t) {
    const int par = t & 1;

    // ---- stage 1: k-quarter burst h load, r,z MFMA partials ----
    const ushort_t* ha = hH + par * BH + (size_t)(b0 + lr) * HDIM + 256 * w + lk;
    sh8 bufa[8];
    #pragma unroll
    for (int i = 0; i < 8; ++i) bufa[i] = *(const sh8*)(ha + i * 32);

    f32x4 accR = (f32x4){0,0,0,0}, accZ = (f32x4){0,0,0,0};
    #pragma unroll
    for (int i = 0; i < 8; ++i) {
      int kk = 8 * w + i;
      int byt = ((lr << 11) + ((kk * 32 + lk) << 1)) ^ ((lr & 7) << 4);
      sh8 rW = *(const sh8*)(lds + byt);
      sh8 zW = *(const sh8*)(lds + 32768 + byt);
      accR = MFMA16(bufa[i], rW, accR);
      accZ = MFMA16(bufa[i], zW, accZ);
    }
    sR[w * 64 + l] = accR;
    sZ[w * 64 + l] = accZ;
    __syncthreads();
    if (w == 0) {
      accR = sR[l] + sR[64 + l] + sR[128 + l] + sR[192 + l];
      accZ = sZ[l] + sZ[64 + l] + sZ[128 + l] + sZ[192 + l];
      #pragma unroll
      for (int j = 0; j < 4; ++j) {
        int b = b0 + rb + j;
        float pr = accR[j] + gxr[j] + br;
        float pz = accZ[j] + gxz[j] + bz;
        float r = 1.f / (1.f + __expf(-pr));
        zreg[j] = 1.f / (1.f + __expf(-pz));
        rhH[b * HDIM + c] = f2bf(r * hold[j]);   // normal store (stays cached)
      }
    }
    ++bar;
    gbar_grp(slots, q, jj, tid, bar);

    // ---- stage 2: k-quarter burst rh load, n MFMA partials (W hi+lo) ----
    const ushort_t* ra = rhH + (size_t)(b0 + lr) * HDIM + 256 * w + lk;
    #pragma unroll
    for (int i = 0; i < 8; ++i) bufa[i] = *(const sh8*)(ra + i * 32);

    f32x4 accN = (f32x4){0,0,0,0};
    #pragma unroll
    for (int i = 0; i < 8; ++i) {
      int kk = 8 * w + i;
      int byt = ((lr << 11) + ((kk * 32 + lk) << 1)) ^ ((lr & 7) << 4);
      sh8 nW = *(const sh8*)(lds + 65536 + byt);
      sh8 nLo = *(const sh8*)(lds + 98304 + byt);
      accN = MFMA16(bufa[i], nW, accN);
      accN = MFMA16(bufa[i], nLo, accN);
    }
    sR[w * 64 + l] = accN;
    __syncthreads();
    if (w == 0) {
      accN = sR[l] + sR[64 + l] + sR[128 + l] + sR[192 + l];
      int tn = (t + 1 < SEQL) ? t + 1 : t;
      const float* gxt1 = gx + (size_t)tn * (BATCH * G3);
      ushort_t* hHn = hH + (par ^ 1) * BH;
      #pragma unroll
      for (int j = 0; j < 4; ++j) {
        int b = b0 + rb + j;
        float pn = accN[j] + gxn[j] + bn;
        float n = tanhf(pn);
        float z = zreg[j];
        float hnew = (1.f - z) * n + z * hold[j];
        hold[j] = hnew;
        __builtin_nontemporal_store(hnew, &Y[(size_t)t * BH + b * HDIM + c]);
        hHn[b * HDIM + c] = f2bf(hnew);          // normal store (stays cached)
        if (t == SEQL - 1) __builtin_nontemporal_store(hnew, &Yh[b * HDIM + c]);
        gxr[j] = __builtin_nontemporal_load(gxt1 + (size_t)b * G3 + c);
        gxz[j] = __builtin_nontemporal_load(gxt1 + (size_t)b * G3 + 1024 + c);
        gxn[j] = __builtin_nontemporal_load(gxt1 + (size_t)b * G3 + 2048 + c);
      }
    }
    if (t < SEQL - 1) {
      ++bar;
      gbar_grp(slots, q, jj, tid, bar);
    }
  }
}

// ---------------- launch ----------------
extern "C" void kernel_launch(void* const* d_in, const int* in_sizes, int n_in,
                              void* d_out, int out_size, void* d_ws, size_t ws_size,
                              hipStream_t stream) {
  const float* input = (const float*)d_in[0];
  const float* h0    = (const float*)d_in[1];
  const float* wih   = (const float*)d_in[2];
  const float* whh   = (const float*)d_in[3];
  const float* bih   = (const float*)d_in[4];
  const float* bhh   = (const float*)d_in[5];

  char* ws = (char*)d_ws;
  size_t o = 0;
  float* gx = (float*)(ws + o);         o += (size_t)AROWS * G3 * 4;
  ushort_t* WihH = (ushort_t*)(ws + o); o += (size_t)G3 * HDIM * 2;
  ushort_t* WihL = (ushort_t*)(ws + o); o += (size_t)G3 * HDIM * 2;
  ushort_t* hH = (ushort_t*)(ws + o);   o += 2 * (size_t)BH * 2;
  ushort_t* rhH = (ushort_t*)(ws + o);  o += (size_t)BH * 2;
  unsigned* slots = (unsigned*)(ws + o); o += (size_t)NWGR * 128;

  float* Y  = (float*)d_out;
  float* Yh = (float*)d_out + (size_t)YSZ;

  (void)hipFuncSetAttribute((const void*)gru_rec,
                            hipFuncAttributeMaxDynamicSharedMemorySize, 139264);

  (void)hipMemsetAsync(slots, 0, (size_t)NWGR * 128, stream);
  cvt_kernel<<<2048, 256, 0, stream>>>(wih, h0, WihH, WihL, hH);
  gemm_gx<<<(AROWS / 128) * (G3 / 128), 256, 0, stream>>>(input, WihH, WihL, bih, gx);
  gru_rec<<<NWGR, 256, 139264, stream>>>(gx, whh, bhh, h0, hH, rhH, Y, Yh, slots);
}